// Round 17
// baseline (16.836 us; speedup 1.0000x reference)
//
#include <hip/hip_runtime.h>

#define NPTS   384
#define DIM    256
#define GA     4              // anchors per block (register-resident fragments)
#define NGRP   (NPTS/GA)      // 96 anchor groups
#define SPLIT  8              // j-slices
#define JS     (NPTS/SPLIT)   // 48 j's per block
#define NBLK   (NGRP*SPLIT)   // 768 blocks = 3/CU
#define MAXK   64             // cap on same-class count (expected ~12)
#define MARGIN 1.0f

__device__ __forceinline__ float wave_red_sum(float p) {
    #pragma unroll
    for (int m = 1; m < 64; m <<= 1) p += __shfl_xor(p, m, 64);
    return p;
}

// R9 structure with the hinge FUSED into the slice-dot groups:
// after the 16-lane xor-reduce every lane holds d, so lane l16 handles
// positive t2 = l16 (+16...) directly from dk LDS. Deletes the dj buffer,
// the separate hinge phase, and the 384-label LDS staging.
__global__ __launch_bounds__(256) void triplet_main(const float* __restrict__ x,
                                                    const int* __restrict__ labels,
                                                    float2* __restrict__ partial) {
    const int g    = blockIdx.x;
    const int s    = blockIdx.y;
    const int tid  = threadIdx.x;
    const int lane = tid & 63;
    const int wid  = tid >> 6;
    const int sub  = lane >> 4;   // row within 4-row group
    const int l16  = lane & 15;   // element-slice lane
    const int a0   = g * GA;

    __shared__ int   kidx[GA][MAXK];
    __shared__ float dk[GA][MAXK];
    __shared__ int   nk_sh[GA];
    __shared__ float wnum[4], wcnt[4];

    // anchor labels (wave-uniform L2-hot loads)
    int la[GA];
    #pragma unroll
    for (int t = 0; t < GA; ++t) la[t] = labels[a0 + t];

    // anchor fragments: fa[t][q] = x[a0+t][l16*4 + q*64 .. +4)
    float4 fa[GA][4];
    #pragma unroll
    for (int t = 0; t < GA; ++t)
        #pragma unroll
        for (int q = 0; q < 4; ++q)
            fa[t][q] = *(const float4*)(x + (size_t)(a0 + t) * DIM + l16 * 4 + q * 64);

    // wave w: ballot-compact positives of anchor a0+w (global label reads)
    {
        const int li = la[wid];
        int base = 0;
        #pragma unroll
        for (int c = 0; c < 6; ++c) {
            const bool m = (labels[c * 64 + lane] == li);
            const unsigned long long mk = __ballot(m);
            const int pre = __popcll(mk & ((1ull << lane) - 1ull));
            const int p = base + pre;
            if (m && p < MAXK) kidx[wid][p] = c * 64 + lane;
            base += __popcll(mk);          // wave-uniform
        }
        if (lane == 0) nk_sh[wid] = (base > MAXK) ? MAXK : base;
    }
    __syncthreads();

    // hoist nk into registers (wave-uniform LDS reads)
    int nkr[GA];
    #pragma unroll
    for (int t = 0; t < GA; ++t) nkr[t] = nk_sh[t];

    // positive dots: 16 groups (wid,sub) cover each anchor's list (1 iter typ.)
    #pragma unroll
    for (int a = 0; a < GA; ++a) {
        const int nk = nkr[a];
        for (int t0 = 0; t0 < nk; t0 += 16) {
            const int t = t0 + wid * 4 + sub;
            if (t < nk) {                    // whole 16-lane group together
                const float* xr = x + (size_t)kidx[a][t] * DIM + l16 * 4;
                float acc = 0.f;
                #pragma unroll
                for (int q = 0; q < 4; ++q) {
                    const float4 rv = *(const float4*)(xr + q * 64);
                    const float d0 = rv.x - fa[a][q].x, d1 = rv.y - fa[a][q].y,
                                d2 = rv.z - fa[a][q].z, d3 = rv.w - fa[a][q].w;
                    acc += d0*d0 + d1*d1 + d2*d2 + d3*d3;
                }
                #pragma unroll
                for (int m = 1; m < 16; m <<= 1) acc += __shfl_xor(acc, m, 64);
                if (l16 == 0) dk[a][t] = acc;
            }
        }
    }
    __syncthreads();

    // slice dots + fused hinge: 16 rows/block-iter, 3 iters
    float num = 0.f, cnt = 0.f;
    #pragma unroll
    for (int u = 0; u < JS / 16; ++u) {
        const int rl = u * 16 + wid * 4 + sub;           // 0..47
        const int lj = labels[s * JS + rl];              // group-uniform, L2-hot
        const float* xr = x + (size_t)(s * JS + rl) * DIM + l16 * 4;
        float4 rx[4];
        #pragma unroll
        for (int q = 0; q < 4; ++q) rx[q] = *(const float4*)(xr + q * 64);
        #pragma unroll
        for (int t = 0; t < GA; ++t) {
            float acc = 0.f;
            #pragma unroll
            for (int q = 0; q < 4; ++q) {
                const float d0 = rx[q].x - fa[t][q].x, d1 = rx[q].y - fa[t][q].y,
                            d2 = rx[q].z - fa[t][q].z, d3 = rx[q].w - fa[t][q].w;
                acc += d0*d0 + d1*d1 + d2*d2 + d3*d3;
            }
            #pragma unroll
            for (int m = 1; m < 16; m <<= 1) acc += __shfl_xor(acc, m, 64);
            // all 16 lanes of the group now hold d(a0+t, j)
            if (lj != la[t]) {
                const int nk = nkr[t];
                const float b = acc - MARGIN;
                for (int t2 = l16; t2 < nk; t2 += 16) {   // 1 step typical (nk<=16)
                    const float h = b + dk[t][t2];        // bcast-friendly LDS
                    num += (h > 0.f) ? h : 0.f;
                }
                if (l16 == 0) cnt += (float)nk;
            }
        }
    }

    // block reduce
    num = wave_red_sum(num);
    cnt = wave_red_sum(cnt);
    if (lane == 0) { wnum[wid] = num; wcnt[wid] = cnt; }
    __syncthreads();
    if (tid == 0)
        partial[blockIdx.y * gridDim.x + blockIdx.x] =
            make_float2(wnum[0] + wnum[1] + wnum[2] + wnum[3],
                        wcnt[0] + wcnt[1] + wcnt[2] + wcnt[3]);
}

// Slim finalize: ONE wave, float4 loads (6/lane), pure shfl butterfly.
__global__ __launch_bounds__(64) void triplet_finalize(const float4* __restrict__ partial4,
                                                       float* __restrict__ out) {
    const int lane = threadIdx.x;
    float n = 0.f, c = 0.f;
    #pragma unroll
    for (int u = 0; u < NBLK / 128; ++u) {               // 768 float2 = 384 float4
        const float4 v = partial4[u * 64 + lane];
        n += v.x + v.z;
        c += v.y + v.w;
    }
    n = wave_red_sum(n);
    c = wave_red_sum(c);
    if (lane == 0) out[0] = n / c;
}

extern "C" void kernel_launch(void* const* d_in, const int* in_sizes, int n_in,
                              void* d_out, int out_size, void* d_ws, size_t ws_size,
                              hipStream_t stream) {
    const float* x      = (const float*)d_in[0];
    const int*   labels = (const int*)d_in[1];
    float*       out    = (float*)d_out;

    float2* partial = (float2*)d_ws;

    dim3 grid(NGRP, SPLIT);
    triplet_main<<<grid, 256, 0, stream>>>(x, labels, partial);
    triplet_finalize<<<1, 64, 0, stream>>>((const float4*)partial, out);
}

// Round 18
// 16.578 us; speedup vs baseline: 1.0156x; 1.0156x over previous
//
#include <hip/hip_runtime.h>

#define NPTS   384
#define DIM    256
#define GA     4              // anchors per block (register-resident fragments)
#define NGRP   (NPTS/GA)      // 96 anchor groups
#define SPLIT  8              // j-slices
#define JS     (NPTS/SPLIT)   // 48 j's per block
#define NBLK   (NGRP*SPLIT)   // 768 blocks = 3/CU
#define MAXK   64             // cap on same-class count (expected ~12)
#define MARGIN 1.0f

__device__ __forceinline__ float wave_red_sum(float p) {
    #pragma unroll
    for (int m = 1; m < 64; m <<= 1) p += __shfl_xor(p, m, 64);
    return p;
}

// R16 structure minus one barrier: positive dots are WAVE-LOCAL (own anchor,
// own kidx -> within-wave LDS dependency, no block sync needed). Single
// __syncthreads before the hinge phase.
__global__ __launch_bounds__(256) void triplet_main(const float* __restrict__ x,
                                                    const int* __restrict__ labels,
                                                    float2* __restrict__ partial) {
    const int g    = blockIdx.x;
    const int s    = blockIdx.y;
    const int tid  = threadIdx.x;
    const int lane = tid & 63;
    const int wid  = tid >> 6;
    const int sub  = lane >> 4;   // row within 4-row group
    const int l16  = lane & 15;   // element-slice lane
    const int a0   = g * GA;

    __shared__ int   lab[NPTS];
    __shared__ int   kidx[GA][MAXK];
    __shared__ float dk[GA][MAXK];
    __shared__ float dj[GA][JS];
    __shared__ int   nk_sh[GA];
    __shared__ float wnum[4], wcnt[4];

    // stage labels for the hinge phase (read after the single barrier)
    for (int j = tid; j < NPTS; j += 256) lab[j] = labels[j];

    // own-anchor fragment (statically indexed; used by pos dots)
    float4 fo[4];
    #pragma unroll
    for (int q = 0; q < 4; ++q)
        fo[q] = *(const float4*)(x + (size_t)(a0 + wid) * DIM + l16 * 4 + q * 64);

    // all-anchor fragments (used by slice dots)
    float4 fa[GA][4];
    #pragma unroll
    for (int t = 0; t < GA; ++t)
        #pragma unroll
        for (int q = 0; q < 4; ++q)
            fa[t][q] = *(const float4*)(x + (size_t)(a0 + t) * DIM + l16 * 4 + q * 64);

    // ballot-compact positives of own anchor; nk kept in register
    int nk_own;
    {
        const int li = labels[a0 + wid];
        int base = 0;
        #pragma unroll
        for (int c = 0; c < 6; ++c) {
            const bool m = (labels[c * 64 + lane] == li);
            const unsigned long long mk = __ballot(m);
            const int pre = __popcll(mk & ((1ull << lane) - 1ull));
            const int p = base + pre;
            if (m && p < MAXK) kidx[wid][p] = c * 64 + lane;
            base += __popcll(mk);          // wave-uniform
        }
        nk_own = (base > MAXK) ? MAXK : base;
        if (lane == 0) nk_sh[wid] = nk_own;
    }

    // positive dots, wave-local: own wave's 4 sub-groups cover own list
    // (within-wave kidx LDS read; compiler orders with lgkmcnt)
    for (int t0 = 0; t0 < nk_own; t0 += 4) {
        const int t = t0 + sub;
        if (t < nk_own) {                   // whole 16-lane group together
            const float* xr = x + (size_t)kidx[wid][t] * DIM + l16 * 4;
            float acc = 0.f;
            #pragma unroll
            for (int q = 0; q < 4; ++q) {
                const float4 rv = *(const float4*)(xr + q * 64);
                const float d0 = rv.x - fo[q].x, d1 = rv.y - fo[q].y,
                            d2 = rv.z - fo[q].z, d3 = rv.w - fo[q].w;
                acc += d0*d0 + d1*d1 + d2*d2 + d3*d3;
            }
            #pragma unroll
            for (int m = 1; m < 16; m <<= 1) acc += __shfl_xor(acc, m, 64);
            if (l16 == 0) dk[wid][t] = acc;
        }
    }

    // slice dots: 16 rows/block-iter, 3 iters; one row load -> 4 anchor dots
    #pragma unroll
    for (int u = 0; u < JS / 16; ++u) {
        const int rl = u * 16 + wid * 4 + sub;           // 0..47
        const float* xr = x + (size_t)(s * JS + rl) * DIM + l16 * 4;
        float4 rx[4];
        #pragma unroll
        for (int q = 0; q < 4; ++q) rx[q] = *(const float4*)(xr + q * 64);
        #pragma unroll
        for (int t = 0; t < GA; ++t) {
            float acc = 0.f;
            #pragma unroll
            for (int q = 0; q < 4; ++q) {
                const float d0 = rx[q].x - fa[t][q].x, d1 = rx[q].y - fa[t][q].y,
                            d2 = rx[q].z - fa[t][q].z, d3 = rx[q].w - fa[t][q].w;
                acc += d0*d0 + d1*d1 + d2*d2 + d3*d3;
            }
            #pragma unroll
            for (int m = 1; m < 16; m <<= 1) acc += __shfl_xor(acc, m, 64);
            if (l16 == 0) dj[t][rl] = acc;
        }
    }
    __syncthreads();                       // the ONLY inter-phase barrier

    // hinge: 192 (a, jl) pairs, threads 0..191 (R16-proven)
    float num = 0.f, cnt = 0.f;
    if (tid < GA * JS) {
        const int a  = tid / JS;
        const int jl = tid % JS;
        const int li = lab[a0 + a];
        if (lab[s * JS + jl] != li) {
            const int nk = nk_sh[a];
            const float b = dj[a][jl] - MARGIN;
            for (int t = 0; t < nk; ++t) {
                const float h = b + dk[a][t];
                num += (h > 0.f) ? h : 0.f;
            }
            cnt = (float)nk;
        }
    }
    num = wave_red_sum(num);
    cnt = wave_red_sum(cnt);
    if (lane == 0) { wnum[wid] = num; wcnt[wid] = cnt; }
    __syncthreads();
    if (tid == 0)
        partial[blockIdx.y * gridDim.x + blockIdx.x] =
            make_float2(wnum[0] + wnum[1] + wnum[2] + wnum[3],
                        wcnt[0] + wcnt[1] + wcnt[2] + wcnt[3]);
}

// Slim finalize: ONE wave, float4 loads (6/lane), pure shfl butterfly.
__global__ __launch_bounds__(64) void triplet_finalize(const float4* __restrict__ partial4,
                                                       float* __restrict__ out) {
    const int lane = threadIdx.x;
    float n = 0.f, c = 0.f;
    #pragma unroll
    for (int u = 0; u < NBLK / 128; ++u) {               // 768 float2 = 384 float4
        const float4 v = partial4[u * 64 + lane];
        n += v.x + v.z;
        c += v.y + v.w;
    }
    n = wave_red_sum(n);
    c = wave_red_sum(c);
    if (lane == 0) out[0] = n / c;
}

extern "C" void kernel_launch(void* const* d_in, const int* in_sizes, int n_in,
                              void* d_out, int out_size, void* d_ws, size_t ws_size,
                              hipStream_t stream) {
    const float* x      = (const float*)d_in[0];
    const int*   labels = (const int*)d_in[1];
    float*       out    = (float*)d_out;

    float2* partial = (float2*)d_ws;

    dim3 grid(NGRP, SPLIT);
    triplet_main<<<grid, 256, 0, stream>>>(x, labels, partial);
    triplet_finalize<<<1, 64, 0, stream>>>((const float4*)partial, out);
}